// Round 3
// baseline (468.006 us; speedup 1.0000x reference)
//
#include <hip/hip_runtime.h>
#include <math.h>

#define N_NODES 50000
#define N_EDGES 800000
#define IN_FEATS 128
#define N_HIDDEN 128
#define N_CLASSES 40
#define SEQ_LEN 20
#define VOCAB 32000
#define BUCKET_CAP 64     // P(in_deg >= 64 | Poisson(16)) ~ 1e-18; guarded anyway

// ---- K1 block roles: [0,HIST) hist | q=b-HIST: q%17==0 edge | else pool
#define HIST_BLOCKS 128   // exclusive 391-node ranges, atomic-free out_cnt
#define HIST_RANGE 391    // ceil(50000/128)
#define EDGE_BLOCKS 782   // ceil(800000 / (256*4)) -> 4 edges/thread
#define POOL_BLOCKS 12500 // 4 nodes per 256-thread block
#define K1_BLOCKS (HIST_BLOCKS + EDGE_BLOCKS + POOL_BLOCKS)  // 13410

// prep kernel block ranges
#define ZERO_BLOCKS 98    // 25088 int4 = 401408 B (in_cnt + out_cnt)
#define W1P_BLOCKS 64     // 16384 packed W1 elements
#define PREP_BLOCKS (ZERO_BLOCKS + W1P_BLOCKS)

#define EGEMM_BLOCKS 500  // 32000 rows / 64 per block

typedef __attribute__((ext_vector_type(8))) short bf16x8;   // 8 bf16 (4 VGPRs)
typedef __attribute__((ext_vector_type(4))) float f32x4;    // MFMA accumulator

// bf16 helpers (RNE)
__device__ inline unsigned short f2bf(float x) {
    union { float f; unsigned int u; } v; v.f = x;
    unsigned int r = v.u + 0x7FFF + ((v.u >> 16) & 1);
    return (unsigned short)(r >> 16);
}
__device__ inline float bf2f(unsigned short b) {
    union { float f; unsigned int u; } v; v.u = ((unsigned int)b) << 16;
    return v.f;
}

// ---------------- workspace layout (bytes) ----------------
//   in_cnt : 0         int[50000]              (zeroed by prep)
//   out_cnt: 200704    int[50000]              (written whole by hist blocks)
//   bucketu: 401408    ushort[50000*64]  6.4 MB (one 128B line per node row)
//   Ep     : 6801408   ushort[32000*128] 8.2 MB (bf16, E' = emb @ W1)
//   G1     : 14993408  ushort[50000*128] 12.8 MB (bf16, pooled E', NO rout)
//   G2     : 27793408  ushort[50000*64]  6.4 MB (bf16, stride-64-padded rows)
//   W1p    : 34193408  ushort[128*128]   32 KB (bf16, MFMA-frag-packed)

// ===== prep: zero counters ∥ pack W1 into MFMA B-frag layout (tiny now).
__global__ __launch_bounds__(256) void prep_kernel(
        int4* __restrict__ zero_region, const float* __restrict__ W1,
        unsigned short* __restrict__ W1p) {
    int b = blockIdx.x;
    int t = threadIdx.x;
    if (b < ZERO_BLOCKS) {
        int i = b * 256 + t;
        if (i < 25088) zero_region[i] = make_int4(0, 0, 0, 0);
    } else {
        int i = (b - ZERO_BLOCKS) * 256 + t;  // exactly 16384
        int tile = i >> 9, rem = i & 511;
        int ln = rem >> 3, j = rem & 7;
        int nt = tile >> 2, kb = tile & 3;
        int k = kb * 32 + ((ln >> 4) << 3) + j;
        int n = nt * 16 + (ln & 15);
        W1p[i] = f2bf(W1[k * 128 + n]);
    }
}

// ===== egemm: E' = emb @ W1 via MFMA bf16 (32000x128 @ 128x128).
__global__ __launch_bounds__(256) void egemm_kernel(
        const float* __restrict__ emb, const unsigned short* __restrict__ W1p,
        unsigned short* __restrict__ Ep) {
    const int wave = threadIdx.x >> 6, lane = threadIdx.x & 63;
    const int quad = lane >> 4, m = lane & 15;
    const int row0 = blockIdx.x * 64 + wave * 16;
    const int arow = row0 + m;                       // < 32000 always
    const float4* ap = (const float4*)(emb + arow * 128 + quad * 8);
    bf16x8 a[4];
    #pragma unroll
    for (int kb = 0; kb < 4; ++kb) {                 // k-cols quad*8 + kb*32
        float4 x = ap[kb * 8];
        float4 y = ap[kb * 8 + 1];
        bf16x8 t;
        t[0] = f2bf(x.x); t[1] = f2bf(x.y); t[2] = f2bf(x.z); t[3] = f2bf(x.w);
        t[4] = f2bf(y.x); t[5] = f2bf(y.y); t[6] = f2bf(y.z); t[7] = f2bf(y.w);
        a[kb] = t;
    }
    const int rbase = row0 + quad * 4;
    #pragma unroll
    for (int nt = 0; nt < 8; ++nt) {
        const unsigned short* wp = W1p + (nt * 4) * 512 + lane * 8;
        bf16x8 b0 = *(const bf16x8*)(wp + 0 * 512);
        bf16x8 b1 = *(const bf16x8*)(wp + 1 * 512);
        bf16x8 b2 = *(const bf16x8*)(wp + 2 * 512);
        bf16x8 b3 = *(const bf16x8*)(wp + 3 * 512);
        f32x4 acc = {0.f, 0.f, 0.f, 0.f};
        acc = __builtin_amdgcn_mfma_f32_16x16x32_bf16(a[0], b0, acc, 0, 0, 0);
        acc = __builtin_amdgcn_mfma_f32_16x16x32_bf16(a[1], b1, acc, 0, 0, 0);
        acc = __builtin_amdgcn_mfma_f32_16x16x32_bf16(a[2], b2, acc, 0, 0, 0);
        acc = __builtin_amdgcn_mfma_f32_16x16x32_bf16(a[3], b3, acc, 0, 0, 0);
        #pragma unroll
        for (int r = 0; r < 4; ++r)
            Ep[(rbase + r) * 128 + nt * 16 + m] = f2bf(acc[r]);
    }
}

// ===== K1: three block roles.
// R14: out_cnt atomics (800K of 1.6M device-scope fabric RMWs) replaced by
// 128 atomic-free hist blocks: each owns an exclusive 391-node range, scans
// all of src (3.2 MB, L2/LLC-resident), counts into a private LDS histogram,
// flushes with plain stores. Hist blocks launch FIRST so they hide under the
// pool/edge bulk. Edge path keeps only the irreducible in_cnt slot atomics.
__global__ __launch_bounds__(256) void build_pool_hist_kernel(
        const int* __restrict__ src, const int* __restrict__ dst,
        int* __restrict__ in_cnt, int* __restrict__ out_cnt,
        unsigned short* __restrict__ bucketu,
        const int* __restrict__ feats, const unsigned short* __restrict__ Ep,
        unsigned short* __restrict__ G1) {
    int b = blockIdx.x;
    int t = threadIdx.x;
    if (b < HIST_BLOCKS) {
        // ---- hist role: out_deg for nodes [lo, lo+391), zero atomics on HBM
        __shared__ unsigned int hc[HIST_RANGE];
        int lo = b * HIST_RANGE;
        for (int i = t; i < HIST_RANGE; i += 256) hc[i] = 0u;
        __syncthreads();
        const int4* s4 = (const int4*)src;
        for (int i = t; i < N_EDGES / 4; i += 256) {
            int4 s = s4[i];
            unsigned d;
            d = (unsigned)(s.x - lo); if (d < (unsigned)HIST_RANGE) atomicAdd(&hc[d], 1u);
            d = (unsigned)(s.y - lo); if (d < (unsigned)HIST_RANGE) atomicAdd(&hc[d], 1u);
            d = (unsigned)(s.z - lo); if (d < (unsigned)HIST_RANGE) atomicAdd(&hc[d], 1u);
            d = (unsigned)(s.w - lo); if (d < (unsigned)HIST_RANGE) atomicAdd(&hc[d], 1u);
        }
        __syncthreads();
        for (int i = t; i < HIST_RANGE; i += 256) {
            int n = lo + i;
            if (n < N_NODES) out_cnt[n] = (int)hc[i];
        }
        return;
    }
    int q = b - HIST_BLOCKS;
    if (q % 17 == 0) {
        // ---- edge path: 4 edges/thread; in_cnt slot-claim atomics + bucket scatter
        int gid = (q / 17) * 256 + t;
        if (gid < N_EDGES / 4) {
            int4 s4 = ((const int4*)src)[gid];
            int4 d4 = ((const int4*)dst)[gid];
            int p0 = atomicAdd(&in_cnt[d4.x], 1);
            int p1 = atomicAdd(&in_cnt[d4.y], 1);
            int p2 = atomicAdd(&in_cnt[d4.z], 1);
            int p3 = atomicAdd(&in_cnt[d4.w], 1);
            if (p0 < BUCKET_CAP) bucketu[d4.x * BUCKET_CAP + p0] = (unsigned short)s4.x;
            if (p1 < BUCKET_CAP) bucketu[d4.y * BUCKET_CAP + p1] = (unsigned short)s4.y;
            if (p2 < BUCKET_CAP) bucketu[d4.z * BUCKET_CAP + p2] = (unsigned short)s4.z;
            if (p3 < BUCKET_CAP) bucketu[d4.w * BUCKET_CAP + p3] = (unsigned short)s4.w;
        }
    } else {
        // ---- pool path: 4 nodes/block, 64 lanes span 128 feats via ushort2
        int pb = q - q / 17 - 1;
        int v = pb * 4 + (t >> 6);
        int lane = t & 63;
        const ushort2* ev = (const ushort2*)Ep;

        int toks[SEQ_LEN];
        const int4* tk4 = (const int4*)(feats + v * SEQ_LEN);
        #pragma unroll
        for (int qq = 0; qq < SEQ_LEN / 4; ++qq) {
            int4 tt = tk4[qq];
            toks[4 * qq + 0] = tt.x;
            toks[4 * qq + 1] = tt.y;
            toks[4 * qq + 2] = tt.z;
            toks[4 * qq + 3] = tt.w;
        }
        int cnt = 0;
        #pragma unroll
        for (int s = 0; s < SEQ_LEN; ++s) cnt += (toks[s] != 0);

        // E' row 0 = emb[0]@W1 = 0, so tok==0 contributes nothing.
        ushort2 g[SEQ_LEN];
        #pragma unroll
        for (int s = 0; s < SEQ_LEN; ++s) g[s] = ev[toks[s] * 64 + lane];
        float a0 = 0.f, a1 = 0.f;
        #pragma unroll
        for (int s = 0; s < SEQ_LEN; ++s) {
            a0 += bf2f(g[s].x);
            a1 += bf2f(g[s].y);
        }
        float sc = 1.f / (float)max(cnt, 1);   // rout applied in spmm1 loop
        ushort2 o = {f2bf(a0 * sc), f2bf(a1 * sc)};
        ((ushort2*)G1)[v * 64 + lane] = o;
    }
}

// ===== spmm1 + gemm2 fused: ushort bucket indices staged in LDS; per-edge
// rout = rsqrt(out_deg[u]) applied in-loop (u is wave-uniform -> out_cnt[u]
// is a broadcast L2 hit); h1 (LDS) -> G2 (stride-64 rows).
__global__ __launch_bounds__(256) void spmm1g2_kernel(
        const int* __restrict__ in_cnt, const int* __restrict__ out_cnt,
        const unsigned short* __restrict__ bucketu, const unsigned short* __restrict__ G,
        const float* __restrict__ b1, const float* __restrict__ W2,
        unsigned short* __restrict__ G2) {
    __shared__ unsigned short idxs[256];
    __shared__ float h1s[4][128];
    int t = threadIdx.x;
    int node = t >> 6, lane = t & 63;
    int v = blockIdx.x * 4 + node;
    idxs[t] = bucketu[blockIdx.x * 256 + t];
    int cnt = in_cnt[v];
    float outc = (float)out_cnt[v];
    float2 bb = ((const float2*)b1)[lane];
    __syncthreads();
    int n = min(cnt, BUCKET_CAP);
    const unsigned short* bk = &idxs[node * BUCKET_CAP];
    const ushort2* Gv = (const ushort2*)G;
    float a0 = 0.f, a1 = 0.f;
    int e = 0;
    for (; e + 16 <= n; e += 16) {
        ushort2 g[16]; float c[16];
        #pragma unroll
        for (int j = 0; j < 16; ++j) {
            int u = bk[e + j];
            g[j] = Gv[u * 64 + lane];
            c[j] = (float)out_cnt[u];
        }
        #pragma unroll
        for (int j = 0; j < 16; ++j) {
            float ro = rsqrtf(fmaxf(c[j], 1.f));
            a0 += bf2f(g[j].x) * ro;
            a1 += bf2f(g[j].y) * ro;
        }
    }
    if (e + 8 <= n) {
        ushort2 g[8]; float c[8];
        #pragma unroll
        for (int j = 0; j < 8; ++j) {
            int u = bk[e + j];
            g[j] = Gv[u * 64 + lane];
            c[j] = (float)out_cnt[u];
        }
        #pragma unroll
        for (int j = 0; j < 8; ++j) {
            float ro = rsqrtf(fmaxf(c[j], 1.f));
            a0 += bf2f(g[j].x) * ro;
            a1 += bf2f(g[j].y) * ro;
        }
        e += 8;
    }
    if (e + 4 <= n) {
        ushort2 g[4]; float c[4];
        #pragma unroll
        for (int j = 0; j < 4; ++j) {
            int u = bk[e + j];
            g[j] = Gv[u * 64 + lane];
            c[j] = (float)out_cnt[u];
        }
        #pragma unroll
        for (int j = 0; j < 4; ++j) {
            float ro = rsqrtf(fmaxf(c[j], 1.f));
            a0 += bf2f(g[j].x) * ro;
            a1 += bf2f(g[j].y) * ro;
        }
        e += 4;
    }
    for (; e < n; ++e) {
        int u = bk[e];
        ushort2 g = Gv[u * 64 + lane];
        float ro = rsqrtf(fmaxf((float)out_cnt[u], 1.f));
        a0 += bf2f(g.x) * ro;
        a1 += bf2f(g.y) * ro;
    }
    float rin = 1.f / sqrtf(fmaxf((float)cnt, 1.f));
    float rout = 1.f / sqrtf(fmaxf(outc, 1.f));
    h1s[node][2 * lane + 0] = fmaxf(a0 * rin + bb.x, 0.f) * rout;
    h1s[node][2 * lane + 1] = fmaxf(a1 * rin + bb.y, 0.f) * rout;
    __syncthreads();
    if (lane < N_CLASSES) {
        const float* hn = h1s[node];
        float s0 = 0.f, s1 = 0.f, s2 = 0.f, s3 = 0.f;
        #pragma unroll 8
        for (int k = 0; k < 128; k += 4) {
            s0 += hn[k + 0] * W2[(k + 0) * N_CLASSES + lane];
            s1 += hn[k + 1] * W2[(k + 1) * N_CLASSES + lane];
            s2 += hn[k + 2] * W2[(k + 2) * N_CLASSES + lane];
            s3 += hn[k + 3] * W2[(k + 3) * N_CLASSES + lane];
        }
        G2[v * 64 + lane] = f2bf((s0 + s1) + (s2 + s3));
    }
}

// layer-2 aggregate (bf16 bucket-gather, stride-64 line-aligned G2 rows) + epilogue
__global__ __launch_bounds__(256) void spmm2_kernel(
        const int* __restrict__ in_cnt, const unsigned short* __restrict__ bucketu,
        const unsigned short* __restrict__ G2, const float* __restrict__ b2,
        float* __restrict__ out) {
    __shared__ unsigned short idxs[256];
    int t = threadIdx.x;
    int node = t >> 6, f = t & 63;
    int v = blockIdx.x * 4 + node;
    idxs[t] = bucketu[blockIdx.x * 256 + t];
    int cnt = in_cnt[v];
    __syncthreads();
    int n = min(cnt, BUCKET_CAP);
    const unsigned short* bk = &idxs[node * BUCKET_CAP];
    if (f < N_CLASSES) {
        float acc = 0.f;
        int e = 0;
        for (; e + 16 <= n; e += 16) {
            unsigned short g[16];
            #pragma unroll
            for (int j = 0; j < 16; ++j) g[j] = G2[bk[e + j] * 64 + f];
            #pragma unroll
            for (int j = 0; j < 16; ++j) acc += bf2f(g[j]);
        }
        if (e + 8 <= n) {
            unsigned short g[8];
            #pragma unroll
            for (int j = 0; j < 8; ++j) g[j] = G2[bk[e + j] * 64 + f];
            #pragma unroll
            for (int j = 0; j < 8; ++j) acc += bf2f(g[j]);
            e += 8;
        }
        if (e + 4 <= n) {
            unsigned short g[4];
            #pragma unroll
            for (int j = 0; j < 4; ++j) g[j] = G2[bk[e + j] * 64 + f];
            #pragma unroll
            for (int j = 0; j < 4; ++j) acc += bf2f(g[j]);
            e += 4;
        }
        for (; e < n; ++e) acc += bf2f(G2[bk[e] * 64 + f]);
        float rin = 1.f / sqrtf(fmaxf((float)cnt, 1.f));
        out[v * N_CLASSES + f] = acc * rin + b2[f];
    }
}

extern "C" void kernel_launch(void* const* d_in, const int* in_sizes, int n_in,
                              void* d_out, int out_size, void* d_ws, size_t ws_size,
                              hipStream_t stream) {
    const int*   feats = (const int*)d_in[0];
    const int*   src   = (const int*)d_in[1];
    const int*   dst   = (const int*)d_in[2];
    const float* emb   = (const float*)d_in[3];
    const float* W1    = (const float*)d_in[4];
    const float* b1    = (const float*)d_in[5];
    const float* W2    = (const float*)d_in[6];
    const float* b2    = (const float*)d_in[7];
    float* out = (float*)d_out;

    char* w = (char*)d_ws;
    int*   in_cnt  = (int*)(w + 0);
    int*   out_cnt = (int*)(w + 200704);
    unsigned short* bucketu = (unsigned short*)(w + 401408);
    unsigned short* Ep      = (unsigned short*)(w + 6801408);
    unsigned short* G1      = (unsigned short*)(w + 14993408);
    unsigned short* G2      = (unsigned short*)(w + 27793408);
    unsigned short* W1p     = (unsigned short*)(w + 34193408);

    // 1) prep: zero counters ∥ W1 frag-pack (tiny)
    prep_kernel<<<PREP_BLOCKS, 256, 0, stream>>>((int4*)w, W1, W1p);
    // 2) E' = emb @ W1 via MFMA (reads emb f32 once, writes 8.2 MB bf16)
    egemm_kernel<<<EGEMM_BLOCKS, 256, 0, stream>>>(emb, W1p, Ep);
    // 3) K1: hist (atomic-free out_cnt) ∥ bucket build (in_cnt atomics) ∥ pool
    build_pool_hist_kernel<<<K1_BLOCKS, 256, 0, stream>>>(
        src, dst, in_cnt, out_cnt, bucketu, feats, Ep, G1);
    // 4) spmm1 (per-edge rout) + gemm2 fused -> G2 (bf16, stride-64 rows)
    spmm1g2_kernel<<<POOL_BLOCKS, 256, 0, stream>>>(in_cnt, out_cnt, bucketu, G1, b1, W2, G2);
    // 5) out = agg(G2)*rin + b2
    spmm2_kernel<<<POOL_BLOCKS, 256, 0, stream>>>(in_cnt, bucketu, G2, b2, out);
}

// Round 4
// 249.334 us; speedup vs baseline: 1.8770x; 1.8770x over previous
//
#include <hip/hip_runtime.h>
#include <math.h>

#define N_NODES 50000
#define N_EDGES 800000
#define IN_FEATS 128
#define N_HIDDEN 128
#define N_CLASSES 40
#define SEQ_LEN 20
#define VOCAB 32000
#define BUCKET_CAP 64     // P(in_deg >= 64 | Poisson(16)) ~ 1e-18; guarded anyway
#define EDGE_BLOCKS 782   // ceil(800000 / (256*4)) -> 4 edges/thread
#define POOL_BLOCKS 12500 // 4 nodes per 256-thread block
#define K1_BLOCKS (EDGE_BLOCKS + POOL_BLOCKS)   // 13282; edge blocks at b%17==0

// prep kernel block ranges
#define ZERO_BLOCKS 98    // 25088 int4 = 401408 B (in_cnt + out_cnt)
#define W1P_BLOCKS 64     // 16384 packed W1 elements
#define PREP_BLOCKS (ZERO_BLOCKS + W1P_BLOCKS)

#define EGEMM_BLOCKS 500  // 32000 rows / 64 per block
#define SCALE_TOTAL (N_NODES * 64)   // G1 as uints: 3,200,000
#define SCALE_BLOCKS 12500

typedef __attribute__((ext_vector_type(8))) short bf16x8;   // 8 bf16 (4 VGPRs)
typedef __attribute__((ext_vector_type(4))) float f32x4;    // MFMA accumulator

#define AS1 __attribute__((address_space(1)))
#define AS3 __attribute__((address_space(3)))

// Direct global->LDS gather: 64 lanes x 4B each, per-lane global source,
// LDS dest = wave-uniform base + lane*4. Zero VGPR cost -> guaranteed MLP
// (the compiler refused to batch register gathers: R12 VGPR stuck at 32).
__device__ __forceinline__ void gld_lds4(const void* g, void* l) {
    __builtin_amdgcn_global_load_lds((const AS1 unsigned int*)g,
                                     (AS3 unsigned int*)l, 4, 0, 0);
}
__device__ __forceinline__ void vm_wait0() {
    asm volatile("s_waitcnt vmcnt(0)" ::: "memory");
}

// bf16 helpers (RNE)
__device__ inline unsigned short f2bf(float x) {
    union { float f; unsigned int u; } v; v.f = x;
    unsigned int r = v.u + 0x7FFF + ((v.u >> 16) & 1);
    return (unsigned short)(r >> 16);
}
__device__ inline float bf2f(unsigned short b) {
    union { float f; unsigned int u; } v; v.u = ((unsigned int)b) << 16;
    return v.f;
}

// ---------------- workspace layout (bytes) ----------------
//   in_cnt : 0         int[50000]              (zeroed by prep)
//   out_cnt: 200704    int[50000]              (zeroed by prep, edge atomics)
//   bucketu: 401408    ushort[50000*64]  6.4 MB (one 128B line per node row)
//   Ep     : 6801408   ushort[32000*128] 8.2 MB (bf16, E' = emb @ W1)
//   G1     : 14993408  ushort[50000*128] 12.8 MB (bf16; scale_g1 folds rout in-place)
//   G2     : 27793408  ushort[50000*64]  6.4 MB (bf16, stride-64-padded rows)
//   W1p    : 34193408  ushort[128*128]   32 KB (bf16, MFMA-frag-packed)

// ===== prep: zero counters ∥ pack W1 into MFMA B-frag layout.
__global__ __launch_bounds__(256) void prep_kernel(
        int4* __restrict__ zero_region, const float* __restrict__ W1,
        unsigned short* __restrict__ W1p) {
    int b = blockIdx.x;
    int t = threadIdx.x;
    if (b < ZERO_BLOCKS) {
        int i = b * 256 + t;
        if (i < 25088) zero_region[i] = make_int4(0, 0, 0, 0);
    } else {
        int i = (b - ZERO_BLOCKS) * 256 + t;  // exactly 16384
        int tile = i >> 9, rem = i & 511;
        int ln = rem >> 3, j = rem & 7;
        int nt = tile >> 2, kb = tile & 3;
        int k = kb * 32 + ((ln >> 4) << 3) + j;
        int n = nt * 16 + (ln & 15);
        W1p[i] = f2bf(W1[k * 128 + n]);
    }
}

// ===== egemm: E' = emb @ W1 via MFMA bf16 (32000x128 @ 128x128).
__global__ __launch_bounds__(256) void egemm_kernel(
        const float* __restrict__ emb, const unsigned short* __restrict__ W1p,
        unsigned short* __restrict__ Ep) {
    const int wave = threadIdx.x >> 6, lane = threadIdx.x & 63;
    const int quad = lane >> 4, m = lane & 15;
    const int row0 = blockIdx.x * 64 + wave * 16;
    const int arow = row0 + m;                       // < 32000 always
    const float4* ap = (const float4*)(emb + arow * 128 + quad * 8);
    bf16x8 a[4];
    #pragma unroll
    for (int kb = 0; kb < 4; ++kb) {                 // k-cols quad*8 + kb*32
        float4 x = ap[kb * 8];
        float4 y = ap[kb * 8 + 1];
        bf16x8 t;
        t[0] = f2bf(x.x); t[1] = f2bf(x.y); t[2] = f2bf(x.z); t[3] = f2bf(x.w);
        t[4] = f2bf(y.x); t[5] = f2bf(y.y); t[6] = f2bf(y.z); t[7] = f2bf(y.w);
        a[kb] = t;
    }
    const int rbase = row0 + quad * 4;
    #pragma unroll
    for (int nt = 0; nt < 8; ++nt) {
        const unsigned short* wp = W1p + (nt * 4) * 512 + lane * 8;
        bf16x8 b0 = *(const bf16x8*)(wp + 0 * 512);
        bf16x8 b1 = *(const bf16x8*)(wp + 1 * 512);
        bf16x8 b2 = *(const bf16x8*)(wp + 2 * 512);
        bf16x8 b3 = *(const bf16x8*)(wp + 3 * 512);
        f32x4 acc = {0.f, 0.f, 0.f, 0.f};
        acc = __builtin_amdgcn_mfma_f32_16x16x32_bf16(a[0], b0, acc, 0, 0, 0);
        acc = __builtin_amdgcn_mfma_f32_16x16x32_bf16(a[1], b1, acc, 0, 0, 0);
        acc = __builtin_amdgcn_mfma_f32_16x16x32_bf16(a[2], b2, acc, 0, 0, 0);
        acc = __builtin_amdgcn_mfma_f32_16x16x32_bf16(a[3], b3, acc, 0, 0, 0);
        #pragma unroll
        for (int r = 0; r < 4; ++r)
            Ep[(rbase + r) * 128 + nt * 16 + m] = f2bf(acc[r]);
    }
}

// ===== K1: bucket-CSC build + out-degree (atomics, R13 form) interleaved
// with mean-pool over E'. R15: pool gathers go DIRECT-TO-LDS (20 issued,
// one vmcnt wait) -> 20 outstanding 256B requests/wave instead of ~4.
__global__ __launch_bounds__(256) void build_pool_kernel(
        const int* __restrict__ src, const int* __restrict__ dst,
        int* __restrict__ in_cnt, int* __restrict__ out_cnt,
        unsigned short* __restrict__ bucketu,
        const int* __restrict__ feats, const unsigned short* __restrict__ Ep,
        unsigned short* __restrict__ G1) {
    __shared__ unsigned int pstage[4][SEQ_LEN][64];   // 20480 B -> 8 blocks/CU
    int b = blockIdx.x;
    int t = threadIdx.x;
    if (b % 17 == 0) {
        // ---- edge path: 4 edges/thread, vectorized int4 loads
        int gid = (b / 17) * 256 + t;
        if (gid < N_EDGES / 4) {
            int4 s4 = ((const int4*)src)[gid];
            int4 d4 = ((const int4*)dst)[gid];
            int p0 = atomicAdd(&in_cnt[d4.x], 1);
            int p1 = atomicAdd(&in_cnt[d4.y], 1);
            int p2 = atomicAdd(&in_cnt[d4.z], 1);
            int p3 = atomicAdd(&in_cnt[d4.w], 1);
            if (p0 < BUCKET_CAP) bucketu[d4.x * BUCKET_CAP + p0] = (unsigned short)s4.x;
            if (p1 < BUCKET_CAP) bucketu[d4.y * BUCKET_CAP + p1] = (unsigned short)s4.y;
            if (p2 < BUCKET_CAP) bucketu[d4.z * BUCKET_CAP + p2] = (unsigned short)s4.z;
            if (p3 < BUCKET_CAP) bucketu[d4.w * BUCKET_CAP + p3] = (unsigned short)s4.w;
            atomicAdd(&out_cnt[s4.x], 1);
            atomicAdd(&out_cnt[s4.y], 1);
            atomicAdd(&out_cnt[s4.z], 1);
            atomicAdd(&out_cnt[s4.w], 1);
        }
    } else {
        // ---- pool path: 4 nodes/block (1 wave each), LDS-staged gathers
        int pb = b - b / 17 - 1;
        int w = t >> 6;
        int v = pb * 4 + w;
        int lane = t & 63;

        int toks[SEQ_LEN];
        const int4* tk4 = (const int4*)(feats + v * SEQ_LEN);
        #pragma unroll
        for (int q = 0; q < SEQ_LEN / 4; ++q) {
            int4 tt = tk4[q];
            toks[4 * q + 0] = tt.x;
            toks[4 * q + 1] = tt.y;
            toks[4 * q + 2] = tt.z;
            toks[4 * q + 3] = tt.w;
        }
        int cnt = 0;
        #pragma unroll
        for (int s = 0; s < SEQ_LEN; ++s) cnt += (toks[s] != 0);

        // issue ALL 20 row-gathers async to LDS (E' row 0 is zero -> pad ok)
        #pragma unroll
        for (int s = 0; s < SEQ_LEN; ++s)
            gld_lds4(Ep + toks[s] * 128 + lane * 2, &pstage[w][s][0]);
        vm_wait0();
        float a0 = 0.f, a1 = 0.f;
        #pragma unroll
        for (int s = 0; s < SEQ_LEN; ++s) {
            unsigned int x = pstage[w][s][lane];
            a0 += bf2f((unsigned short)(x & 0xffffu));
            a1 += bf2f((unsigned short)(x >> 16));
        }
        float sc = 1.f / (float)max(cnt, 1);   // rout folded by scale_g1
        ushort2 o = {f2bf(a0 * sc), f2bf(a1 * sc)};
        ((ushort2*)G1)[v * 64 + lane] = o;
    }
}

// ===== scale_g1: G1[row] *= rsqrt(out_deg[row]) in place (fold rout once
// at write-side: 50K rows instead of 800K per-edge broadcast loads+rsqrt).
__global__ __launch_bounds__(256) void scale_g1_kernel(
        const int* __restrict__ out_cnt, unsigned int* __restrict__ G1u) {
    int i = blockIdx.x * 256 + threadIdx.x;
    if (i >= SCALE_TOTAL) return;
    int row = i >> 6;                         // 64 uints per row
    float ro = rsqrtf(fmaxf((float)out_cnt[row], 1.f));
    unsigned int x = G1u[i];
    unsigned short lo = f2bf(bf2f((unsigned short)(x & 0xffffu)) * ro);
    unsigned short hi = f2bf(bf2f((unsigned short)(x >> 16)) * ro);
    G1u[i] = (unsigned int)lo | ((unsigned int)hi << 16);
}

// ===== spmm1 + gemm2 fused. R15: G1 row-gathers direct-to-LDS, 16 deep;
// G1 is pre-scaled so the inner loop is pure gather+add. All LDS regions
// are wave-private -> no __syncthreads at all.
__global__ __launch_bounds__(256) void spmm1g2_kernel(
        const int* __restrict__ in_cnt, const int* __restrict__ out_cnt,
        const unsigned short* __restrict__ bucketu, const unsigned short* __restrict__ G,
        const float* __restrict__ b1, const float* __restrict__ W2,
        unsigned short* __restrict__ G2) {
    __shared__ unsigned short idxs[256];
    __shared__ float h1s[4][128];
    __shared__ unsigned int stg[4][16][64];    // 16 KB gather stage
    int t = threadIdx.x;
    int node = t >> 6, lane = t & 63;
    int v = blockIdx.x * 4 + node;
    idxs[t] = bucketu[blockIdx.x * 256 + t];   // wave-local row of node `node`
    int cnt = in_cnt[v];
    float outc = (float)out_cnt[v];
    float2 bb = ((const float2*)b1)[lane];
    int n = min(cnt, BUCKET_CAP);
    const unsigned short* bk = &idxs[node * BUCKET_CAP];
    float a0 = 0.f, a1 = 0.f;
    for (int base = 0; base < n; base += 16) {
        int m = min(16, n - base);
        #pragma unroll 4
        for (int j = 0; j < m; ++j) {
            int u = bk[base + j];
            gld_lds4(G + u * 128 + lane * 2, &stg[node][j][0]);
        }
        vm_wait0();
        #pragma unroll 4
        for (int j = 0; j < m; ++j) {
            unsigned int x = stg[node][j][lane];
            a0 += bf2f((unsigned short)(x & 0xffffu));
            a1 += bf2f((unsigned short)(x >> 16));
        }
    }
    float rin = rsqrtf(fmaxf((float)cnt, 1.f));
    float rout = rsqrtf(fmaxf(outc, 1.f));
    h1s[node][2 * lane + 0] = fmaxf(a0 * rin + bb.x, 0.f) * rout;
    h1s[node][2 * lane + 1] = fmaxf(a1 * rin + bb.y, 0.f) * rout;
    // h1s[node] written entirely by this wave -> no barrier needed
    if (lane < N_CLASSES) {
        const float* hn = h1s[node];
        float s0 = 0.f, s1 = 0.f, s2 = 0.f, s3 = 0.f;
        #pragma unroll 8
        for (int k = 0; k < 128; k += 4) {
            s0 += hn[k + 0] * W2[(k + 0) * N_CLASSES + lane];
            s1 += hn[k + 1] * W2[(k + 1) * N_CLASSES + lane];
            s2 += hn[k + 2] * W2[(k + 2) * N_CLASSES + lane];
            s3 += hn[k + 3] * W2[(k + 3) * N_CLASSES + lane];
        }
        G2[v * 64 + lane] = f2bf((s0 + s1) + (s2 + s3));
    }
}

// ===== spmm2: layer-2 aggregate + epilogue. R15: paired-row direct-to-LDS
// gathers (lanes 0-31 -> row j, lanes 32-63 -> row j+1; 128B each).
__global__ __launch_bounds__(256) void spmm2_kernel(
        const int* __restrict__ in_cnt, const unsigned short* __restrict__ bucketu,
        const unsigned short* __restrict__ G2, const float* __restrict__ b2,
        float* __restrict__ out) {
    __shared__ unsigned short idxs[256];
    __shared__ unsigned short stg[4][16][64];  // 8 KB
    int t = threadIdx.x;
    int node = t >> 6, f = t & 63;
    int v = blockIdx.x * 4 + node;
    idxs[t] = bucketu[blockIdx.x * 256 + t];   // wave-local
    int cnt = in_cnt[v];
    int n = min(cnt, BUCKET_CAP);
    const unsigned short* bk = &idxs[node * BUCKET_CAP];
    int half = f >> 5, sub = f & 31;
    float acc = 0.f;
    for (int base = 0; base < n; base += 16) {
        int m = min(16, n - base);
        #pragma unroll 2
        for (int j = 0; j < m; j += 2) {
            int u0 = bk[base + j];
            int u1 = (j + 1 < m) ? bk[base + j + 1] : u0;
            int u = half ? u1 : u0;
            gld_lds4(G2 + u * 64 + sub * 2, &stg[node][j][0]);
        }
        vm_wait0();
        if (f < N_CLASSES) {
            #pragma unroll 4
            for (int j = 0; j < m; ++j) acc += bf2f(stg[node][j][f]);
        }
    }
    if (f < N_CLASSES) {
        float rin = rsqrtf(fmaxf((float)cnt, 1.f));
        out[v * N_CLASSES + f] = acc * rin + b2[f];
    }
}

extern "C" void kernel_launch(void* const* d_in, const int* in_sizes, int n_in,
                              void* d_out, int out_size, void* d_ws, size_t ws_size,
                              hipStream_t stream) {
    const int*   feats = (const int*)d_in[0];
    const int*   src   = (const int*)d_in[1];
    const int*   dst   = (const int*)d_in[2];
    const float* emb   = (const float*)d_in[3];
    const float* W1    = (const float*)d_in[4];
    const float* b1    = (const float*)d_in[5];
    const float* W2    = (const float*)d_in[6];
    const float* b2    = (const float*)d_in[7];
    float* out = (float*)d_out;

    char* w = (char*)d_ws;
    int*   in_cnt  = (int*)(w + 0);
    int*   out_cnt = (int*)(w + 200704);
    unsigned short* bucketu = (unsigned short*)(w + 401408);
    unsigned short* Ep      = (unsigned short*)(w + 6801408);
    unsigned short* G1      = (unsigned short*)(w + 14993408);
    unsigned short* G2      = (unsigned short*)(w + 27793408);
    unsigned short* W1p     = (unsigned short*)(w + 34193408);

    // 1) prep: zero counters ∥ W1 frag-pack
    prep_kernel<<<PREP_BLOCKS, 256, 0, stream>>>((int4*)w, W1, W1p);
    // 2) E' = emb @ W1 via MFMA
    egemm_kernel<<<EGEMM_BLOCKS, 256, 0, stream>>>(emb, W1p, Ep);
    // 3) K1: bucket build + degrees (atomics) ∥ LDS-staged pool -> G1
    build_pool_kernel<<<K1_BLOCKS, 256, 0, stream>>>(
        src, dst, in_cnt, out_cnt, bucketu, feats, Ep, G1);
    // 4) fold rout into G1 (in place)
    scale_g1_kernel<<<SCALE_BLOCKS, 256, 0, stream>>>(out_cnt, (unsigned int*)G1);
    // 5) spmm1 + gemm2 fused -> G2
    spmm1g2_kernel<<<POOL_BLOCKS, 256, 0, stream>>>(in_cnt, out_cnt, bucketu, G1, b1, W2, G2);
    // 6) out = agg(G2)*rin + b2
    spmm2_kernel<<<POOL_BLOCKS, 256, 0, stream>>>(in_cnt, bucketu, G2, b2, out);
}